// Round 1
// baseline (214.013 us; speedup 1.0000x reference)
//
#include <hip/hip_runtime.h>
#include <stdint.h>

// Problem constants (reference: B=2, D=128, H=64, W=64)
#define BN 2
#define DN 128
#define MN 4096                          // H*W pixels per image
#define TOTAL_INV (1.0f / 33554432.0f)   // 1 / (B*M*N)
#define LDSTR 48                         // LDS row stride (elems): 32 data + 16 pad
                                         // -> frag ds_read_b128 bank-even, writes 2-way (free)

typedef __attribute__((ext_vector_type(8))) short short8;       // 8 bf16 = 4 VGPRs
typedef __attribute__((ext_vector_type(4))) float f32x4;
typedef __attribute__((ext_vector_type(4))) unsigned int u32x4;

__device__ static inline unsigned short f2bf(float x) {
  // round-to-nearest-even f32 -> bf16 (inputs are finite normals) — identical to prior version
  unsigned int u = __float_as_uint(x);
  u += 0x7fffu + ((u >> 16) & 1u);
  return (unsigned short)(u >> 16);
}
__device__ static inline unsigned int pk2(float a, float b) {
  return (unsigned int)f2bf(a) | ((unsigned int)f2bf(b) << 16);
}

// Single fused kernel: inline f32->bf16 transpose-staging + MFMA GEMM + hinge loss + mean.
// C[m,n] = sum_d A[b,d,m] * B[b,d,n]  (source is [B,D,M], m-contiguous)
// grid: (N/128, M/128, B), block 256 (4 waves as 2x2; each wave 64x64 = 4x4 MFMAs)
__global__ __launch_bounds__(256) void fused_loss(
    const float* __restrict__ A, const float* __restrict__ Bg,
    const void* __restrict__ maskp, float* __restrict__ out) {
  __shared__ __align__(16) unsigned short As[128 * LDSTR];  // 12 KB, [m][k] k-contig
  __shared__ __align__(16) unsigned short Bs[128 * LDSTR];  // 12 KB, [n][k] k-contig
  __shared__ float red[4];
  __shared__ int mask_is_u8;

  const int tid  = threadIdx.x;
  const int lane = tid & 63;
  const int wave = tid >> 6;
  const int wm = wave >> 1, wn = wave & 1;
  const int quad = lane >> 4;
  const int l16  = lane & 15;
  const int bn = blockIdx.x, bm = blockIdx.y, bz = blockIdx.z;

  // ---- mask dtype sniff: int32 {0,1} has zero bytes at offset%4!=0 ----
  if (tid == 0) mask_is_u8 = 0;
  __syncthreads();
  if (((const unsigned int*)maskp)[tid] & 0xFFFFFF00u) mask_is_u8 = 1;  // benign race
  // (barriers before use happen inside the K-loop)

  // Staging mapping: thread owns column m (resp. n) = tid&127, d-half = (tid>>7)*16.
  // Per d-row instruction a wave loads 64 consecutive f32 = 256 B, fully coalesced.
  const int sm = tid & 127;
  const int dh = (tid >> 7) << 4;                    // 0 or 16
  const float* Ac = A  + (size_t)bz * DN * MN + (size_t)(bm * 128) + sm;
  const float* Bc = Bg + (size_t)bz * DN * MN + (size_t)(bn * 128) + sm;

  f32x4 acc[4][4];
#pragma unroll
  for (int i = 0; i < 4; ++i)
#pragma unroll
    for (int j = 0; j < 4; ++j) acc[i][j] = (f32x4){0.f, 0.f, 0.f, 0.f};

  unsigned short* Ad = As + sm * LDSTR + dh;         // 16B-aligned (sm*96 + dh*2)
  unsigned short* Bd = Bs + sm * LDSTR + dh;
  const unsigned short* Ar = As + (wm * 64 + l16) * LDSTR + quad * 8;
  const unsigned short* Br = Bs + (wn * 64 + l16) * LDSTR + quad * 8;

  for (int kt = 0; kt < 4; ++kt) {
    const int k0 = kt * 32 + dh;
    float ra[16], rb[16];
#pragma unroll
    for (int j = 0; j < 16; ++j) ra[j] = Ac[(size_t)(k0 + j) * MN];
#pragma unroll
    for (int j = 0; j < 16; ++j) rb[j] = Bc[(size_t)(k0 + j) * MN];
    // pack 16 k-ascending bf16 per tensor, two ds_write_b128 each
    u32x4 w;
    w = (u32x4){pk2(ra[0], ra[1]),  pk2(ra[2], ra[3]),
                pk2(ra[4], ra[5]),  pk2(ra[6], ra[7])};
    *(u32x4*)Ad = w;
    w = (u32x4){pk2(ra[8], ra[9]),  pk2(ra[10], ra[11]),
                pk2(ra[12], ra[13]), pk2(ra[14], ra[15])};
    *(u32x4*)(Ad + 8) = w;
    w = (u32x4){pk2(rb[0], rb[1]),  pk2(rb[2], rb[3]),
                pk2(rb[4], rb[5]),  pk2(rb[6], rb[7])};
    *(u32x4*)Bd = w;
    w = (u32x4){pk2(rb[8], rb[9]),  pk2(rb[10], rb[11]),
                pk2(rb[12], rb[13]), pk2(rb[14], rb[15])};
    *(u32x4*)(Bd + 8) = w;
    __syncthreads();

    // fragment reads + MFMA: verbatim structure from the known-good kernel
    short8 af[4], bf[4];
#pragma unroll
    for (int mi = 0; mi < 4; ++mi)
      af[mi] = *(const short8*)(Ar + mi * 16 * LDSTR);   // ds_read_b128, bank-even
#pragma unroll
    for (int ni = 0; ni < 4; ++ni)
      bf[ni] = *(const short8*)(Br + ni * 16 * LDSTR);
#pragma unroll
    for (int mi = 0; mi < 4; ++mi)
#pragma unroll
      for (int ni = 0; ni < 4; ++ni)
        acc[mi][ni] = __builtin_amdgcn_mfma_f32_16x16x32_bf16(
            af[mi], bf[ni], acc[mi][ni], 0, 0, 0);
    __syncthreads();
  }

  // ---- epilogue: hinge loss under mask, block reduction, one atomic ----
  // C/D layout: col = lane&15 (n), row = quad*4 + r (m)
  const size_t mbase =
      ((size_t)bz * MN + (size_t)(bm * 128 + wm * 64)) * MN + (size_t)(bn * 128 + wn * 64);
  const int* mi32 = (const int*)maskp;
  const unsigned char* mu8 = (const unsigned char*)maskp;
  const int u8 = mask_is_u8;
  float lsum = 0.0f;
#pragma unroll
  for (int mi = 0; mi < 4; ++mi) {
#pragma unroll
    for (int ni = 0; ni < 4; ++ni) {
      f32x4 v = acc[mi][ni];
#pragma unroll
      for (int r = 0; r < 4; ++r) {
        int m = mi * 16 + quad * 4 + r;
        int n = ni * 16 + l16;
        size_t idx = mbase + (size_t)m * MN + n;
        int msk = u8 ? (int)mu8[idx] : mi32[idx];
        float dot = v[r];
        float pos = fmaxf(0.0f, 1.0f - dot) * 250.0f;
        float neg = fmaxf(0.0f, dot - 0.2f);
        lsum += msk ? pos : neg;
      }
    }
  }
#pragma unroll
  for (int off = 32; off > 0; off >>= 1) lsum += __shfl_xor(lsum, off);
  if (lane == 0) red[wave] = lsum;
  __syncthreads();
  if (tid == 0) {
    float t = (red[0] + red[1] + red[2] + red[3]) * TOTAL_INV;
    atomicAdd(out, t);   // device-scope float atomic; d_out zeroed by memset
  }
}

extern "C" void kernel_launch(void* const* d_in, const int* in_sizes, int n_in,
                              void* d_out, int out_size, void* d_ws, size_t ws_size,
                              hipStream_t stream) {
  const float* d0 = (const float*)d_in[0];
  const float* d1 = (const float*)d_in[1];
  const void* mask = d_in[2];

  // d_out is re-poisoned to 0xAA before every replay -> must zero it here
  hipMemsetAsync(d_out, 0, sizeof(float), stream);

  // NOTE: d_ws intentionally unused — single fused kernel, no bf16 round-trip.
  dim3 g(MN / 128, MN / 128, BN), b(256);
  fused_loss<<<g, b, 0, stream>>>(d0, d1, mask, (float*)d_out);
}

// Round 3
// 210.314 us; speedup vs baseline: 1.0176x; 1.0176x over previous
//
#include <hip/hip_runtime.h>
#include <stdint.h>

// Problem constants (reference: B=2, D=128, H=64, W=64)
#define BN 2
#define DN 128
#define MN 4096                          // H*W pixels per image
#define TOTAL_INV (1.0f / 33554432.0f)   // 1 / (B*M*N)

typedef __attribute__((ext_vector_type(8))) short short8;   // 8 bf16 = 4 VGPRs
typedef __attribute__((ext_vector_type(4))) float f32x4;

__device__ static inline unsigned short f2bf(float x) {
  // round-to-nearest-even f32 -> bf16 (inputs are finite normals)
  unsigned int u = __float_as_uint(x);
  u += 0x7fffu + ((u >> 16) & 1u);
  return (unsigned short)(u >> 16);
}

__device__ static inline void async16(const void* g, void* l) {
  // 16B global -> LDS direct copy (dest = wave-uniform base + lane*16)
  __builtin_amdgcn_global_load_lds(
      (const __attribute__((address_space(1))) void*)g,
      (__attribute__((address_space(3))) void*)l, 16, 0, 0);
}

// [B, D, M] f32  ->  [B, M, D] bf16(ushort), 64x64 LDS tile transpose (proven round-0)
__global__ __launch_bounds__(256) void transpose_cvt(
    const float* __restrict__ s0, const float* __restrict__ s1,
    unsigned short* __restrict__ o0, unsigned short* __restrict__ o1) {
  __shared__ float tile[64][65];          // +1 pad: conflict-free transpose
  const int tx = threadIdx.x & 63;
  const int ty = threadIdx.x >> 6;        // 0..3 (wave id)
  const int m0 = blockIdx.x * 64;
  const int d0 = blockIdx.y * 64;
  const int b  = blockIdx.z & 1;
  const float* src = (blockIdx.z >> 1) ? s1 : s0;
  unsigned short* dst = (blockIdx.z >> 1) ? o1 : o0;
  src += (size_t)b * DN * MN;
  dst += (size_t)b * MN * DN;
#pragma unroll
  for (int i = 0; i < 16; ++i) {
    int dr = i * 4 + ty;
    tile[dr][tx] = src[(size_t)(d0 + dr) * MN + m0 + tx];  // 256B coalesced / wave
  }
  __syncthreads();
#pragma unroll
  for (int i = 0; i < 16; ++i) {
    int mr = i * 4 + ty;
    dst[(size_t)(m0 + mr) * DN + d0 + tx] = f2bf(tile[tx][mr]);  // 128B coalesced
  }
}

// Fused bf16 MFMA GEMM (C = A * B^T) + hinge loss + mean.
// v2b: double-buffered panel staging (stage t+1 || compute t) + LDS-staged u8 mask
// tile so the 33.5 MB mask HBM stream overlaps the whole K-loop.
// FIX vs v2: compute() takes the BUFFER index (kt & 1), not the K-tile index —
// v2 called compute(2)/compute(3) which read past As[2] (OOB garbage -> inf).
// grid: (N/128, M/128, B), block 256 (4 waves, 2x2; each wave 64x64 = 4x4 MFMAs)
__global__ __launch_bounds__(256) void gemm_loss(
    const unsigned short* __restrict__ A, const unsigned short* __restrict__ Bm,
    const void* __restrict__ maskp, float* __restrict__ out) {
  __shared__ __align__(16) unsigned short As[2][128 * 32];  // 2 x 8 KB, [m][k] k-contig
  __shared__ __align__(16) unsigned short Bs[2][128 * 32];  // 2 x 8 KB, [n][k] k-contig
  __shared__ __align__(16) unsigned char Ms[128 * 128];     // 16 KB u8 mask tile
  __shared__ float red[4];
  __shared__ int mask_is_u8;

  const int tid  = threadIdx.x;
  const int lane = tid & 63;
  const int wave = tid >> 6;
  const int wm = wave >> 1, wn = wave & 1;
  const int quad = lane >> 4;
  const int l16  = lane & 15;
  const int bn = blockIdx.x, bm = blockIdx.y, bz = blockIdx.z;

  // ---- mask dtype sniff: int32 {0,1} has zero bytes at offset%4!=0 ----
  if (tid == 0) mask_is_u8 = 0;
  __syncthreads();
  if (((const unsigned int*)maskp)[tid] & 0xFFFFFF00u) mask_is_u8 = 1;  // benign race
  // (flag becomes block-uniform at the barrier after stage(0,0))

  const unsigned short* Ab = A  + (size_t)bz * MN * DN + (size_t)(bm * 128) * DN;
  const unsigned short* Bb = Bm + (size_t)bz * MN * DN + (size_t)(bn * 128) * DN;

  f32x4 acc[4][4];
#pragma unroll
  for (int i = 0; i < 4; ++i)
#pragma unroll
    for (int j = 0; j < 4; ++j) acc[i][j] = (f32x4){0.f, 0.f, 0.f, 0.f};

  // stage 128x32 bf16 panel pair into buffer sel: 512 x 16B chunks, 2/thread each
  auto stage = [&](int sel, int kt) {
    const int k0 = kt * 32;
#pragma unroll
    for (int p = 0; p < 2; ++p) {
      int c = tid + p * 256;
      int row = c >> 2;      // 4 chunks (64B) per row
      int cq  = c & 3;
      async16(Ab + (size_t)row * DN + k0 + cq * 8, &As[sel][c * 8]);
      async16(Bb + (size_t)row * DN + k0 + cq * 8, &Bs[sel][c * 8]);
    }
  };
  auto compute = [&](int sel) {            // sel = BUFFER index (0 or 1)
    short8 af[4], bf[4];
#pragma unroll
    for (int mi = 0; mi < 4; ++mi)   // ds_read_b128: contiguous 1KB per wave, bank-even
      af[mi] = *(const short8*)(&As[sel][(wm * 64 + mi * 16 + l16) * 32 + quad * 8]);
#pragma unroll
    for (int ni = 0; ni < 4; ++ni)
      bf[ni] = *(const short8*)(&Bs[sel][(wn * 64 + ni * 16 + l16) * 32 + quad * 8]);
#pragma unroll
    for (int mi = 0; mi < 4; ++mi)
#pragma unroll
      for (int ni = 0; ni < 4; ++ni)
        acc[mi][ni] = __builtin_amdgcn_mfma_f32_16x16x32_bf16(
            af[mi], bf[ni], acc[mi][ni], 0, 0, 0);
  };

  stage(0, 0);
  __syncthreads();                       // kt0 panels ready; sniff flag valid+uniform
  const int u8 = mask_is_u8;

  // issue the block's whole 16 KB mask tile now (u8 path): flows under the K-loop
  const unsigned char* mg = (const unsigned char*)maskp +
      ((size_t)bz * MN + (size_t)(bm * 128)) * MN + (size_t)(bn * 128);
  if (u8) {
#pragma unroll
    for (int p = 0; p < 4; ++p) {
      int c = tid + p * 256;             // 1024 chunks: row=c>>3, 16B col chunk
      int row = c >> 3, off = (c & 7) * 16;
      async16(mg + (size_t)row * MN + off, Ms + c * 16);
    }
  }
  stage(1, 1);
  compute(0);                            // kt0 from buf0
  __syncthreads();                       // kt1 + mask drained
  stage(0, 2);
  compute(1);                            // kt1 from buf1
  __syncthreads();                       // kt2 drained
  stage(1, 3);
  compute(0);                            // kt2 from buf0
  __syncthreads();                       // kt3 drained
  compute(1);                            // kt3 from buf1

  // ---- epilogue: hinge loss under mask, block reduction, one atomic ----
  // C/D layout: col = lane&15 (n), row = quad*4 + r (m)   [wave-relative 64x64]
  const size_t gbase =
      ((size_t)bz * MN + (size_t)(bm * 128 + wm * 64)) * MN + (size_t)(bn * 128 + wn * 64);
  const int* mi32 = (const int*)maskp;
  const int lrow0 = wm * 64, lcol0 = wn * 64;
  float lsum = 0.0f;
#pragma unroll
  for (int mi = 0; mi < 4; ++mi) {
#pragma unroll
    for (int ni = 0; ni < 4; ++ni) {
      f32x4 v = acc[mi][ni];
#pragma unroll
      for (int r = 0; r < 4; ++r) {
        int m = mi * 16 + quad * 4 + r;
        int n = ni * 16 + l16;
        int msk = u8 ? (int)Ms[(lrow0 + m) * 128 + lcol0 + n]
                     : mi32[gbase + (size_t)m * MN + n];
        float dot = v[r];
        float pos = fmaxf(0.0f, 1.0f - dot) * 250.0f;
        float neg = fmaxf(0.0f, dot - 0.2f);
        lsum += msk ? pos : neg;
      }
    }
  }
#pragma unroll
  for (int off = 32; off > 0; off >>= 1) lsum += __shfl_xor(lsum, off);
  if (lane == 0) red[wave] = lsum;
  __syncthreads();
  if (tid == 0) {
    float t = (red[0] + red[1] + red[2] + red[3]) * TOTAL_INV;
    atomicAdd(out, t);   // device-scope float atomic; d_out zeroed by memset
  }
}

extern "C" void kernel_launch(void* const* d_in, const int* in_sizes, int n_in,
                              void* d_out, int out_size, void* d_ws, size_t ws_size,
                              hipStream_t stream) {
  const float* d0 = (const float*)d_in[0];
  const float* d1 = (const float*)d_in[1];
  const void* mask = d_in[2];
  float* out = (float*)d_out;

  unsigned short* Aw = (unsigned short*)d_ws;            // [B, M, D] bf16, 2 MB
  unsigned short* Bw = Aw + (size_t)BN * MN * DN;        // [B, M, D] bf16, 2 MB

  // d_out is re-poisoned to 0xAA before every replay -> must zero it here
  hipMemsetAsync(d_out, 0, sizeof(float), stream);

  dim3 g1(MN / 64, DN / 64, BN * 2), b1(256);
  transpose_cvt<<<g1, b1, 0, stream>>>(d0, d1, Aw, Bw);

  dim3 g2(MN / 128, MN / 128, BN), b2(256);
  gemm_loss<<<g2, b2, 0, stream>>>(Aw, Bw, mask, out);
}